// Round 3
// baseline (332.695 us; speedup 1.0000x reference)
//
#include <hip/hip_runtime.h>

#define DIMC 256
#define BSZ  32
#define MDIM 2048
#define NDIM 2048

typedef __attribute__((ext_vector_type(8))) short bf16x8;   // 8 bf16
typedef __attribute__((ext_vector_type(4))) float f32x4;    // MFMA acc

static __device__ __forceinline__ unsigned short f2bf(float x) {
  unsigned int u = __float_as_uint(x);
  u += 0x7fffu + ((u >> 16) & 1u);          // RNE
  return (unsigned short)(u >> 16);
}
static __device__ __forceinline__ float bf2f(unsigned short h) {
  return __uint_as_float(((unsigned int)h) << 16);
}

// async global->LDS, 16 B per lane; ldsptr must be wave-uniform base
static __device__ __forceinline__ void gl_lds16(const void* g, void* l) {
  __builtin_amdgcn_global_load_lds(
      (const __attribute__((address_space(1))) unsigned int*)g,
      (__attribute__((address_space(3))) unsigned int*)l, 16, 0, 0);
}

// ---------------------------------------------------------------------------
// Wt[e][c] = bf16(W[c][e])
// ---------------------------------------------------------------------------
__global__ __launch_bounds__(256) void wt_kernel(
    const float* __restrict__ W, unsigned short* __restrict__ Wt) {
  const int e = blockIdx.x, c = threadIdx.x;
  Wt[e * 256 + c] = f2bf(W[c * 256 + e]);
}

// ---------------------------------------------------------------------------
// value fp32 -> bf16 (pure convert, layout unchanged [b][d][n])
// ---------------------------------------------------------------------------
__global__ __launch_bounds__(256) void vconv_kernel(
    const float* __restrict__ v, unsigned short* __restrict__ vb) {
  const size_t i = ((size_t)blockIdx.x * 256 + threadIdx.x) * 8;
  float4 a = *(const float4*)(v + i);
  float4 b = *(const float4*)(v + i + 4);
  unsigned short t[8] __attribute__((aligned(16)));
  t[0] = f2bf(a.x); t[1] = f2bf(a.y); t[2] = f2bf(a.z); t[3] = f2bf(a.w);
  t[4] = f2bf(b.x); t[5] = f2bf(b.y); t[6] = f2bf(b.z); t[7] = f2bf(b.w);
  *(uint4*)(vb + i) = *(const uint4*)t;
}

// ---------------------------------------------------------------------------
// phiq: D[e][m] = sum_c Wt[e][c] * query[c][m];  store relu(D/16) -> phi_q[m][e]
// A = Wt via global_load_lds (unpadded [128][32]); B = query transpose-staged.
// ---------------------------------------------------------------------------
__global__ __launch_bounds__(256) void phiq_kernel(
    const float* __restrict__ X, const unsigned short* __restrict__ Wt,
    unsigned short* __restrict__ phi) {
  __shared__ unsigned short As[128 * 32];  // [e][c] unpadded (global_load_lds)
  __shared__ unsigned short Bs[128 * 40];  // [m][c] padded
  const int b = blockIdx.z;
  const int m0 = blockIdx.x * 128;
  const int e0 = blockIdx.y * 128;
  const int t = threadIdx.x;
  const int lane = t & 63, wave = t >> 6;
  const int wr = wave >> 1, wc = wave & 1;
  const int q = lane >> 4, l15 = lane & 15;
  const float* Xb = X + (size_t)b * DIMC * MDIM;
  const int a1row = t >> 2, a1k = (t & 3) << 3;  // seg t, seg t+256 -> +64 rows
  const int midx = t & 127, ch = (t >> 7) << 4;
  f32x4 acc[4][4];
#pragma unroll
  for (int i = 0; i < 4; ++i)
#pragma unroll
    for (int j = 0; j < 4; ++j) acc[i][j] = (f32x4){0.f, 0.f, 0.f, 0.f};

  for (int k0 = 0; k0 < DIMC; k0 += 32) {
    __syncthreads();
    gl_lds16(Wt + (size_t)(e0 + a1row) * DIMC + k0 + a1k, &As[wave * 512]);
    gl_lds16(Wt + (size_t)(e0 + a1row + 64) * DIMC + k0 + a1k,
             &As[2048 + wave * 512]);
    {
      const float* src = Xb + (size_t)(k0 + ch) * MDIM + m0 + midx;
      unsigned short tmp[16] __attribute__((aligned(16)));
#pragma unroll
      for (int i = 0; i < 16; ++i) tmp[i] = f2bf(src[(size_t)i * MDIM]);
      *(uint4*)&Bs[midx * 40 + ch] = *(const uint4*)&tmp[0];
      *(uint4*)&Bs[midx * 40 + ch + 8] = *(const uint4*)&tmp[8];
    }
    __syncthreads();
    bf16x8 a[4], bv[4];
#pragma unroll
    for (int i = 0; i < 4; ++i)
      a[i] = *(const bf16x8*)&As[(wr * 64 + i * 16 + l15) * 32 + q * 8];
#pragma unroll
    for (int j = 0; j < 4; ++j)
      bv[j] = *(const bf16x8*)&Bs[(wc * 64 + j * 16 + l15) * 40 + q * 8];
#pragma unroll
    for (int i = 0; i < 4; ++i)
#pragma unroll
      for (int j = 0; j < 4; ++j)
        acc[i][j] =
            __builtin_amdgcn_mfma_f32_16x16x32_bf16(a[i], bv[j], acc[i][j], 0, 0, 0);
  }
  unsigned short* dst = phi + (size_t)b * MDIM * DIMC;  // [m][e]
#pragma unroll
  for (int i = 0; i < 4; ++i)
#pragma unroll
    for (int j = 0; j < 4; ++j) {
      const int m = m0 + wc * 64 + j * 16 + l15;
#pragma unroll
      for (int r = 0; r < 4; ++r) {
        const int e = e0 + wr * 64 + i * 16 + q * 4 + r;
        float v = acc[i][j][r];
        v = v > 0.f ? v * 0.0625f : 0.f;
        dst[(size_t)m * DIMC + e] = f2bf(v);
      }
    }
}

// ---------------------------------------------------------------------------
// phik: D[e][n] = sum_c Wt[e][c] * key[c][n]; store relu -> phi_k[e][n]
// ---------------------------------------------------------------------------
__global__ __launch_bounds__(256) void phik_kernel(
    const float* __restrict__ X, const unsigned short* __restrict__ Wt,
    unsigned short* __restrict__ phi) {
  __shared__ unsigned short As[128 * 32];
  __shared__ unsigned short Bs[128 * 40];
  const int b = blockIdx.z;
  const int n0 = blockIdx.x * 128;
  const int e0 = blockIdx.y * 128;
  const int t = threadIdx.x;
  const int lane = t & 63, wave = t >> 6;
  const int wr = wave >> 1, wc = wave & 1;
  const int q = lane >> 4, l15 = lane & 15;
  const float* Xb = X + (size_t)b * DIMC * NDIM;
  const int a1row = t >> 2, a1k = (t & 3) << 3;
  const int nidx = t & 127, ch = (t >> 7) << 4;
  f32x4 acc[4][4];
#pragma unroll
  for (int i = 0; i < 4; ++i)
#pragma unroll
    for (int j = 0; j < 4; ++j) acc[i][j] = (f32x4){0.f, 0.f, 0.f, 0.f};

  for (int k0 = 0; k0 < DIMC; k0 += 32) {
    __syncthreads();
    gl_lds16(Wt + (size_t)(e0 + a1row) * DIMC + k0 + a1k, &As[wave * 512]);
    gl_lds16(Wt + (size_t)(e0 + a1row + 64) * DIMC + k0 + a1k,
             &As[2048 + wave * 512]);
    {
      const float* src = Xb + (size_t)(k0 + ch) * NDIM + n0 + nidx;
      unsigned short tmp[16] __attribute__((aligned(16)));
#pragma unroll
      for (int i = 0; i < 16; ++i) tmp[i] = f2bf(src[(size_t)i * NDIM]);
      *(uint4*)&Bs[nidx * 40 + ch] = *(const uint4*)&tmp[0];
      *(uint4*)&Bs[nidx * 40 + ch + 8] = *(const uint4*)&tmp[8];
    }
    __syncthreads();
    bf16x8 a[4], bv[4];
#pragma unroll
    for (int i = 0; i < 4; ++i)
      a[i] = *(const bf16x8*)&As[(wr * 64 + i * 16 + l15) * 32 + q * 8];
#pragma unroll
    for (int j = 0; j < 4; ++j)
      bv[j] = *(const bf16x8*)&Bs[(wc * 64 + j * 16 + l15) * 40 + q * 8];
#pragma unroll
    for (int i = 0; i < 4; ++i)
#pragma unroll
      for (int j = 0; j < 4; ++j)
        acc[i][j] =
            __builtin_amdgcn_mfma_f32_16x16x32_bf16(a[i], bv[j], acc[i][j], 0, 0, 0);
  }
  unsigned short* dst = phi + (size_t)b * DIMC * NDIM;  // [e][n]
#pragma unroll
  for (int i = 0; i < 4; ++i)
#pragma unroll
    for (int j = 0; j < 4; ++j) {
      const int n = n0 + wc * 64 + j * 16 + l15;
#pragma unroll
      for (int r = 0; r < 4; ++r) {
        const int e = e0 + wr * 64 + i * 16 + q * 4 + r;
        float v = acc[i][j][r];
        dst[(size_t)e * NDIM + n] = f2bf(v > 0.f ? v : 0.f);
      }
    }
}

// ---------------------------------------------------------------------------
// rowsum[b*256+e] = sum_n phi_k[b][e][n]
// ---------------------------------------------------------------------------
__global__ __launch_bounds__(256) void rowsum_kernel(
    const unsigned short* __restrict__ phi_k, float* __restrict__ rowsum) {
  const int row = blockIdx.x;
  const unsigned short* p = phi_k + (size_t)row * NDIM;
  uint4 v = *(const uint4*)(p + threadIdx.x * 8);
  const unsigned short* u = (const unsigned short*)&v;
  float s = 0.f;
#pragma unroll
  for (int i = 0; i < 8; ++i) s += bf2f(u[i]);
  __shared__ float red[256];
  red[threadIdx.x] = s;
  __syncthreads();
  for (int w = 128; w >= 1; w >>= 1) {
    if (threadIdx.x < w) red[threadIdx.x] += red[threadIdx.x + w];
    __syncthreads();
  }
  if (threadIdx.x == 0) rowsum[row] = red[0];
}

// ---------------------------------------------------------------------------
// kv partial: kv_acc[b][d][e] += sum_{n in slice} vb[b][d][n]*phi_k[b][e][n]
// grid (2,2,128): z = b*4+slice, K-slice = 512. Pure bf16 + global_load_lds.
// ---------------------------------------------------------------------------
__global__ __launch_bounds__(256) void kv_kernel(
    const unsigned short* __restrict__ vb,
    const unsigned short* __restrict__ phi_k, float* __restrict__ kv_acc) {
  __shared__ unsigned short As[128 * 32];  // [d][n]
  __shared__ unsigned short Bs[128 * 32];  // [e][n]
  const int z = blockIdx.z;
  const int b = z >> 2, slice = z & 3;
  const int d0 = blockIdx.x * 128, e0 = blockIdx.y * 128;
  const int t = threadIdx.x;
  const int lane = t & 63, wave = t >> 6;
  const int wr = wave >> 1, wc = wave & 1;
  const int q = lane >> 4, l15 = lane & 15;
  const unsigned short* Ab = vb + (size_t)b * DIMC * NDIM;
  const unsigned short* Bb = phi_k + (size_t)b * DIMC * NDIM;
  const int a1row = t >> 2, a1k = (t & 3) << 3;
  f32x4 acc[4][4];
#pragma unroll
  for (int i = 0; i < 4; ++i)
#pragma unroll
    for (int j = 0; j < 4; ++j) acc[i][j] = (f32x4){0.f, 0.f, 0.f, 0.f};

  const int nbeg = slice * 512;
  for (int n0 = nbeg; n0 < nbeg + 512; n0 += 32) {
    __syncthreads();
    gl_lds16(Ab + (size_t)(d0 + a1row) * NDIM + n0 + a1k, &As[wave * 512]);
    gl_lds16(Ab + (size_t)(d0 + a1row + 64) * NDIM + n0 + a1k,
             &As[2048 + wave * 512]);
    gl_lds16(Bb + (size_t)(e0 + a1row) * NDIM + n0 + a1k, &Bs[wave * 512]);
    gl_lds16(Bb + (size_t)(e0 + a1row + 64) * NDIM + n0 + a1k,
             &Bs[2048 + wave * 512]);
    __syncthreads();
    bf16x8 a[4], bv[4];
#pragma unroll
    for (int i = 0; i < 4; ++i)
      a[i] = *(const bf16x8*)&As[(wr * 64 + i * 16 + l15) * 32 + q * 8];
#pragma unroll
    for (int j = 0; j < 4; ++j)
      bv[j] = *(const bf16x8*)&Bs[(wc * 64 + j * 16 + l15) * 32 + q * 8];
#pragma unroll
    for (int i = 0; i < 4; ++i)
#pragma unroll
      for (int j = 0; j < 4; ++j)
        acc[i][j] =
            __builtin_amdgcn_mfma_f32_16x16x32_bf16(a[i], bv[j], acc[i][j], 0, 0, 0);
  }
  float* kva = kv_acc + (size_t)b * DIMC * DIMC;
#pragma unroll
  for (int i = 0; i < 4; ++i)
#pragma unroll
    for (int j = 0; j < 4; ++j) {
      const int e = e0 + wc * 64 + j * 16 + l15;
#pragma unroll
      for (int r = 0; r < 4; ++r) {
        const int d = d0 + wr * 64 + i * 16 + q * 4 + r;
        atomicAdd(&kva[(size_t)d * DIMC + e], acc[i][j][r]);
      }
    }
}

// ---------------------------------------------------------------------------
// kv_t bf16 <- kv_acc fp32
// ---------------------------------------------------------------------------
__global__ __launch_bounds__(256) void kvcvt_kernel(
    const float* __restrict__ acc, unsigned short* __restrict__ kvt) {
  const size_t i = ((size_t)blockIdx.x * 256 + threadIdx.x) * 4;
  float4 a = *(const float4*)(acc + i);
  unsigned short t[4] __attribute__((aligned(8)));
  t[0] = f2bf(a.x); t[1] = f2bf(a.y); t[2] = f2bf(a.z); t[3] = f2bf(a.w);
  *(uint2*)(kvt + i) = *(const uint2*)t;
}

// ---------------------------------------------------------------------------
// scale[b][m] = 1/(sum_e phi_q[b][m][e]*rowsum[b][e] + 1e-8), one wave per m
// ---------------------------------------------------------------------------
__global__ __launch_bounds__(256) void scale_kernel(
    const unsigned short* __restrict__ phi_q, const float* __restrict__ rowsum,
    float* __restrict__ scale) {
  const int gw = blockIdx.x * 4 + (threadIdx.x >> 6);
  const int b = gw >> 11, m = gw & 2047;
  const int lane = threadIdx.x & 63;
  const unsigned short* p = phi_q + ((size_t)b * MDIM + m) * DIMC + lane * 4;
  uint2 v = *(const uint2*)p;
  const unsigned short* u = (const unsigned short*)&v;
  float4 r = *(const float4*)(rowsum + b * DIMC + lane * 4);
  float s = bf2f(u[0]) * r.x + bf2f(u[1]) * r.y + bf2f(u[2]) * r.z +
            bf2f(u[3]) * r.w;
#pragma unroll
  for (int off = 32; off >= 1; off >>= 1) s += __shfl_down(s, off, 64);
  if (lane == 0) scale[(size_t)b * MDIM + m] = 1.f / (s + 1e-8f);
}

// ---------------------------------------------------------------------------
// out[b][d][m] = scale[m] * sum_e kv_t[d][e] * phi_q[m][e]; pure bf16 GEMM.
// ---------------------------------------------------------------------------
__global__ __launch_bounds__(256) void out_kernel(
    const unsigned short* __restrict__ kv_t,
    const unsigned short* __restrict__ phi_q, const float* __restrict__ scale,
    float* __restrict__ out) {
  __shared__ unsigned short As[128 * 32];  // [d][e]
  __shared__ unsigned short Bs[128 * 32];  // [m][e]
  const int b = blockIdx.z;
  const int m0 = blockIdx.x * 128;
  const int d0 = blockIdx.y * 128;
  const int t = threadIdx.x;
  const int lane = t & 63, wave = t >> 6;
  const int wr = wave >> 1, wc = wave & 1;
  const int q = lane >> 4, l15 = lane & 15;
  const unsigned short* Ab = kv_t + (size_t)b * DIMC * DIMC;
  const unsigned short* Bb = phi_q + (size_t)b * MDIM * DIMC;
  const int a1row = t >> 2, a1k = (t & 3) << 3;
  f32x4 acc[4][4];
#pragma unroll
  for (int i = 0; i < 4; ++i)
#pragma unroll
    for (int j = 0; j < 4; ++j) acc[i][j] = (f32x4){0.f, 0.f, 0.f, 0.f};

  for (int k0 = 0; k0 < DIMC; k0 += 32) {
    __syncthreads();
    gl_lds16(Ab + (size_t)(d0 + a1row) * DIMC + k0 + a1k, &As[wave * 512]);
    gl_lds16(Ab + (size_t)(d0 + a1row + 64) * DIMC + k0 + a1k,
             &As[2048 + wave * 512]);
    gl_lds16(Bb + (size_t)(m0 + a1row) * DIMC + k0 + a1k, &Bs[wave * 512]);
    gl_lds16(Bb + (size_t)(m0 + a1row + 64) * DIMC + k0 + a1k,
             &Bs[2048 + wave * 512]);
    __syncthreads();
    bf16x8 a[4], bv[4];
#pragma unroll
    for (int i = 0; i < 4; ++i)
      a[i] = *(const bf16x8*)&As[(wr * 64 + i * 16 + l15) * 32 + q * 8];
#pragma unroll
    for (int j = 0; j < 4; ++j)
      bv[j] = *(const bf16x8*)&Bs[(wc * 64 + j * 16 + l15) * 32 + q * 8];
#pragma unroll
    for (int i = 0; i < 4; ++i)
#pragma unroll
      for (int j = 0; j < 4; ++j)
        acc[i][j] =
            __builtin_amdgcn_mfma_f32_16x16x32_bf16(a[i], bv[j], acc[i][j], 0, 0, 0);
  }
  float* ob = out + (size_t)b * DIMC * MDIM;
  const float* scb = scale + (size_t)b * MDIM;
#pragma unroll
  for (int j = 0; j < 4; ++j) {
    const int m = m0 + wc * 64 + j * 16 + l15;
    const float sc = scb[m];
#pragma unroll
    for (int i = 0; i < 4; ++i) {
#pragma unroll
      for (int r = 0; r < 4; ++r) {
        const int d = d0 + wr * 64 + i * 16 + q * 4 + r;
        ob[(size_t)d * MDIM + m] = acc[i][j][r] * sc;
      }
    }
  }
}

extern "C" void kernel_launch(void* const* d_in, const int* in_sizes, int n_in,
                              void* d_out, int out_size, void* d_ws, size_t ws_size,
                              hipStream_t stream) {
  const float* query = (const float*)d_in[0];
  const float* key   = (const float*)d_in[1];
  const float* value = (const float*)d_in[2];
  const float* W     = (const float*)d_in[3];
  float* out = (float*)d_out;

  // Workspace layout (~114 MB)
  unsigned short* Wt    = (unsigned short*)d_ws;             // 256*256
  unsigned short* v_bf  = Wt + 65536;                        // B*256*N
  unsigned short* phi_q = v_bf + (size_t)BSZ * DIMC * NDIM;  // B*M*256 (m-major)
  unsigned short* phi_k = phi_q + (size_t)BSZ * MDIM * DIMC; // B*256*N (e-major)
  unsigned short* kv_t  = phi_k + (size_t)BSZ * DIMC * NDIM; // B*256*256 (d-major)
  float* kv_acc = (float*)(kv_t + (size_t)BSZ * DIMC * DIMC);// B*256*256 fp32
  float* rowsum = kv_acc + (size_t)BSZ * DIMC * DIMC;
  float* scale  = rowsum + BSZ * DIMC;

  hipMemsetAsync(kv_acc, 0, (size_t)BSZ * DIMC * DIMC * sizeof(float), stream);
  hipLaunchKernelGGL(wt_kernel, dim3(256), dim3(256), 0, stream, W, Wt);
  hipLaunchKernelGGL(vconv_kernel, dim3(8192), dim3(256), 0, stream, value, v_bf);
  hipLaunchKernelGGL(phiq_kernel, dim3(MDIM / 128, DIMC / 128, BSZ), dim3(256),
                     0, stream, query, Wt, phi_q);
  hipLaunchKernelGGL(phik_kernel, dim3(NDIM / 128, DIMC / 128, BSZ), dim3(256),
                     0, stream, key, Wt, phi_k);
  hipLaunchKernelGGL(rowsum_kernel, dim3(BSZ * DIMC), dim3(256), 0, stream,
                     phi_k, rowsum);
  hipLaunchKernelGGL(kv_kernel, dim3(2, 2, BSZ * 4), dim3(256), 0, stream,
                     v_bf, phi_k, kv_acc);
  hipLaunchKernelGGL(kvcvt_kernel, dim3(2048), dim3(256), 0, stream, kv_acc,
                     kv_t);
  hipLaunchKernelGGL(scale_kernel, dim3(BSZ * MDIM / 4), dim3(256), 0, stream,
                     phi_q, rowsum, scale);
  hipLaunchKernelGGL(out_kernel, dim3(MDIM / 128, DIMC / 128, BSZ), dim3(256),
                     0, stream, kv_t, phi_q, scale, out);
}